// Round 5
// baseline (377.737 us; speedup 1.0000x reference)
//
#include <hip/hip_runtime.h>
#include <hip/hip_bf16.h>
#include <hip/hip_cooperative_groups.h>
#include <math.h>

namespace cg = cooperative_groups;

// Problem constants (from reference)
constexpr int N_ENT = 100000;
constexpr int NEDGE = 1600000;
constexpr int BATCH = 8192;

// Bucketed CSR placement
constexpr int NBUCK   = 256;
constexpr int KNODE   = 391;                      // 256*391 >= N_ENT
constexpr int TILE    = 4096;
constexpr int NTILE   = (NEDGE + TILE - 1) / TILE; // 391
constexpr int BUCKCAP = 8192;                     // fixed bucket region

constexpr int NBLK_G = (N_ENT + 63) / 64;         // 1563 (64-row MLP tiles)

// [R18 journal] Top-5 exposed __amd_rocclr_fillBufferAligned @41us x3
// (256MiB harness re-poison of ws) — ~123us of dur_us is FIXED overhead
// outside kernel control. Controllable time ~110us: reduce1 50 (random-
// gather floor), rest ~60 across 7 launches. This round: preprocessing
// (ginit+bin+unbinC+packw+prep) collapsed into ONE cooperative launch with
// 3 grid.sync phases; reduce1 remerged. 8 -> 4 dispatches.

// MFMA fragment types (gfx950; 8 bf16 = 4 VGPRs, 4 f32 acc)
typedef __attribute__((ext_vector_type(8))) short bf16x8;
typedef __attribute__((ext_vector_type(4))) float f32x4;

// bf16 helpers (RNE pack, exact unpack)
__device__ inline unsigned short f2b(float x) {
    unsigned int u = __float_as_uint(x);
    unsigned int r = (u + 0x7fffu + ((u >> 16) & 1u)) >> 16;
    return (unsigned short)r;
}
__device__ inline float blo(unsigned int p) { return __uint_as_float(p << 16); }
__device__ inline float bhi(unsigned int p) { return __uint_as_float(p & 0xffff0000u); }

// ---------------------------------------------------------------------------
// Workspace layout (4-byte units; 41.6 MB of the 256MiB ws):
//  dinv      : [100000, 200000)
//  row_start : [200000, 300001)
//  gcursor   : [300004, 300260)
//  w1p       : [300656, 304752)    uint4[1024] packed W1 B-frags (bf16)
//  w2p       : [304752, 308848)    uint4[1024] packed W2 B-frags (bf16)
//  srcs      : [308848, 1908848)
//  emb_b     : [1908848, 3508864)  ushort[(N+1)*64]
//  zb        : [3508864, 6711936)  ushort[100096*64] bf16 z (padded rows)
//  h2b       : [6711936, 8311968)  ushort[(N+1)*64]
//  temp      : [8311968, 10409120) uint[256*8192]

// K0 (cooperative, grid=391x256): phases A..D with grid.sync between.
//  A: block 0 inits gcursor; B: bin edges into fixed bucket regions;
//  C: blocks<256 unbin (LDS-staged count+scan+place -> row_start+srcs),
//     blocks 256..263 pack W1/W2 into MFMA B-frag order;
//  D: prep — renorm*dinv premultiplied bf16 entity rows (quarter-wave/row).
__global__ __launch_bounds__(256) void pre_k(const int* __restrict__ edges,
                                             const float* __restrict__ W1g,
                                             const float* __restrict__ W2g,
                                             uint4* __restrict__ w1p,
                                             uint4* __restrict__ w2p,
                                             int* __restrict__ gcursor,
                                             unsigned int* __restrict__ temp,
                                             int* __restrict__ row_start,
                                             int* __restrict__ srcs,
                                             const float* __restrict__ emb,
                                             float* __restrict__ dinv,
                                             unsigned short* __restrict__ emb_b) {
    cg::grid_group grid = cg::this_grid();
    __shared__ unsigned int st[BUCKCAP];   // 32 KB bucket stage (phase C)
    __shared__ int cntS[KNODE];            // B: bucket cnt[256] / C: node cnt
    __shared__ int curS[KNODE];            // B: gb[256]         / C: node cur
    __shared__ int bsS[NBUCK];             // B: off[256]        / C: base scan
    int b   = blockIdx.x;
    int tid = threadIdx.x;

    // ---- phase A: gcursor init + row_start sentinel
    if (b == 0) {
        gcursor[tid] = tid * BUCKCAP;
        if (tid == 0) row_start[N_ENT] = NEDGE;
    }
    grid.sync();

    // ---- phase B: bin (each block one 4096-edge tile)
    {
        int base = b * TILE;
        unsigned int val[16];
        unsigned int bpk[4] = {0u, 0u, 0u, 0u};
        cntS[tid] = 0;
        __syncthreads();
#pragma unroll
        for (int i = 0; i < 16; ++i) {
            int e = base + i * 256 + tid;
            unsigned int bk = 0u;
            if (e < NEDGE) {
                int s  = edges[e];
                int d  = edges[NEDGE + e];
                int bb = d / KNODE;            // magic-mul
                int dl = d - bb * KNODE;
                val[i] = ((unsigned int)s << 9) | (unsigned int)dl;
                bk = (unsigned int)bb;
                atomicAdd(&cntS[bb], 1);
            } else {
                val[i] = 0xffffffffu;          // invalid marker (valid < 2^26)
            }
            bpk[i >> 2] |= bk << ((i & 3) * 8);
        }
        __syncthreads();
        if (cntS[tid] > 0) curS[tid] = atomicAdd(&gcursor[tid], cntS[tid]);
        bsS[tid] = 0;
        __syncthreads();
#pragma unroll
        for (int i = 0; i < 16; ++i) {
            if (val[i] != 0xffffffffu) {
                int bk = (int)((bpk[i >> 2] >> ((i & 3) * 8)) & 255u);
                int p  = atomicAdd(&bsS[bk], 1);
                temp[curS[bk] + p] = val[i];
            }
        }
    }
    grid.sync();

    // ---- phase C: unbin (blocks 0..255) / weight pack (blocks 256..263)
    if (b < NBUCK) {
        // bucket_base: in-block exclusive scan of per-bucket counts
        int myc = gcursor[tid] - tid * BUCKCAP;
        bsS[tid] = myc;
        __syncthreads();
        for (int off = 1; off < NBUCK; off <<= 1) {
            int x = (tid >= off) ? bsS[tid - off] : 0;
            __syncthreads();
            bsS[tid] += x;
            __syncthreads();
        }
        int node0 = b * KNODE;
        int nn    = N_ENT - node0; if (nn > KNODE) nn = KNODE;
        int tbeg  = b * BUCKCAP;
        int m     = gcursor[b] - tbeg;
        int bucket_base = bsS[b] - m;
        for (int i = tid; i < KNODE; i += 256) cntS[i] = 0;
        __syncthreads();
        // stage + histogram (single global read of temp)
        for (int i = tid; i < m; i += 256) {
            unsigned int x = temp[tbeg + i];
            st[i] = x;
            atomicAdd(&cntS[x & 511u], 1);
        }
        __syncthreads();
        // wave 0: 391-element prefix scan (7/lane) -> cur + row_start
        if (tid < 64) {
            int lane = tid;
            int loc[7];
            int s = 0;
#pragma unroll
            for (int j = 0; j < 7; ++j) {
                int idx = lane * 7 + j;
                int d = (idx < nn) ? cntS[idx] : 0;
                loc[j] = s;
                s += d;
            }
            int v = s;
#pragma unroll
            for (int o = 1; o < 64; o <<= 1) {
                int x = __shfl_up(v, o, 64);
                if (lane >= o) v += x;
            }
            int pfx = v - s;
#pragma unroll
            for (int j = 0; j < 7; ++j) {
                int idx = lane * 7 + j;
                if (idx < nn) {
                    int rs = bucket_base + pfx + loc[j];
                    curS[idx] = rs;
                    row_start[node0 + idx] = rs;
                }
            }
        }
        __syncthreads();
        // placement from LDS
        for (int i = tid; i < m; i += 256) {
            unsigned int x = st[i];
            int dl  = (int)(x & 511u);
            int pos = atomicAdd(&curS[dl], 1);
            srcs[pos] = (int)(x >> 9);
        }
    } else if (b < NBUCK + 8) {
        // weight pack: 8 blocks -> 2048 threads
        int t    = (b - NBUCK) * 256 + tid;
        int e    = t & 1023;
        int lane = e & 63, cs = e >> 6;
        int li   = lane & 15, quad = lane >> 4;
        unsigned short v[8];
        if (t < 1024) {
            int ct = cs >> 1, s = cs & 1;
            int kb = s * 32 + quad * 8;
            int n  = ct * 16 + li;
#pragma unroll
            for (int j = 0; j < 8; ++j) v[j] = f2b(W1g[(kb + j) * 128 + n]);
            uint4 p;
            p.x = (unsigned)v[0] | ((unsigned)v[1] << 16);
            p.y = (unsigned)v[2] | ((unsigned)v[3] << 16);
            p.z = (unsigned)v[4] | ((unsigned)v[5] << 16);
            p.w = (unsigned)v[6] | ((unsigned)v[7] << 16);
            w1p[e] = p;
        } else {
            int ct = cs >> 2, s = cs & 3;
            int kb = s * 32 + quad * 8;
            int n  = ct * 16 + li;
#pragma unroll
            for (int j = 0; j < 8; ++j) v[j] = f2b(W2g[(kb + j) * 64 + n]);
            uint4 p;
            p.x = (unsigned)v[0] | ((unsigned)v[1] << 16);
            p.y = (unsigned)v[2] | ((unsigned)v[3] << 16);
            p.z = (unsigned)v[4] | ((unsigned)v[5] << 16);
            p.w = (unsigned)v[6] | ((unsigned)v[7] << 16);
            w2p[e] = p;
        }
    }
    grid.sync();

    // ---- phase D: prep (quarter-wave per row, float4 loads)
    {
        int lane  = tid & 63;
        int qid   = lane >> 4, li = lane & 15;
        int gw    = (b * 256 + tid) >> 6;            // global wave id
        int nw    = (NTILE * 256) >> 6;              // 1564 waves
        for (int n4 = gw; n4 <= N_ENT / 4; n4 += nw) {
            int n = n4 * 4 + qid;
            if (n > N_ENT) continue;
            unsigned short* dst = emb_b + (size_t)n * 64 + li * 4;
            if (n == N_ENT) {
                uint2 z; z.x = 0u; z.y = 0u;
                *(uint2*)dst = z;
                continue;
            }
            float4 v = *(const float4*)(emb + (size_t)n * 64 + li * 4);
            float s = v.x * v.x + v.y * v.y + v.z * v.z + v.w * v.w;
            s += __shfl_xor(s, 1, 64);
            s += __shfl_xor(s, 2, 64);
            s += __shfl_xor(s, 4, 64);
            s += __shfl_xor(s, 8, 64);
            float nrm = sqrtf(s);
            float sc  = nrm > 1.0f ? 1.0f / nrm : 1.0f;
            int   deg = row_start[n + 1] - row_start[n];
            float dv  = 1.0f / sqrtf((float)(deg + 1));
            if (li == 0) dinv[n] = dv;
            float mch = sc * dv;
            unsigned int h0 = f2b(mch * v.x);
            unsigned int h1 = f2b(mch * v.y);
            unsigned int h2 = f2b(mch * v.z);
            unsigned int h3 = f2b(mch * v.w);
            uint2 p;
            p.x = h0 | (h1 << 16);
            p.y = h2 | (h3 << 16);
            *(uint2*)dst = p;
        }
    }
}

// K1: layer-1 aggregate (uint2, 16 lanes/row — best measured, ~49.8us;
// pinned at the random-128B-row gather floor across 3 structural variants).
__global__ __launch_bounds__(256) void reduce1_k(const int* __restrict__ row_start,
                                                 const int* __restrict__ srcs,
                                                 const unsigned short* __restrict__ emb_b,
                                                 const float* __restrict__ dinv,
                                                 unsigned short* __restrict__ zb) {
    int gt   = blockIdx.x * 256 + threadIdx.x;
    int dst  = gt >> 6;
    int lane = threadIdx.x & 63;
    int sub  = lane >> 4;
    int li   = lane & 15;
    int beg = row_start[dst];
    int end = row_start[dst + 1];
    float4 acc = make_float4(0.f, 0.f, 0.f, 0.f);
    for (int base = beg; base < end; base += 64) {
        int cnt = end - base; if (cnt > 64) cnt = 64;
        int s_v = (base + lane < end) ? srcs[base + lane] : N_ENT;
        for (int jj = 0; jj < cnt; jj += 16) {
            int s0 = __shfl(s_v, jj + sub,      64);
            int s1 = __shfl(s_v, jj + 4 + sub,  64);
            int s2 = __shfl(s_v, jj + 8 + sub,  64);
            int s3 = __shfl(s_v, jj + 12 + sub, 64);
            uint2 p0 = *(const uint2*)(emb_b + (size_t)s0 * 64 + li * 4);
            uint2 p1 = *(const uint2*)(emb_b + (size_t)s1 * 64 + li * 4);
            uint2 p2 = *(const uint2*)(emb_b + (size_t)s2 * 64 + li * 4);
            uint2 p3 = *(const uint2*)(emb_b + (size_t)s3 * 64 + li * 4);
            acc.x += blo(p0.x) + blo(p1.x) + blo(p2.x) + blo(p3.x);
            acc.y += bhi(p0.x) + bhi(p1.x) + bhi(p2.x) + bhi(p3.x);
            acc.z += blo(p0.y) + blo(p1.y) + blo(p2.y) + blo(p3.y);
            acc.w += bhi(p0.y) + bhi(p1.y) + bhi(p2.y) + bhi(p3.y);
        }
    }
    acc.x += __shfl_xor(acc.x, 16, 64); acc.y += __shfl_xor(acc.y, 16, 64);
    acc.z += __shfl_xor(acc.z, 16, 64); acc.w += __shfl_xor(acc.w, 16, 64);
    acc.x += __shfl_xor(acc.x, 32, 64); acc.y += __shfl_xor(acc.y, 32, 64);
    acc.z += __shfl_xor(acc.z, 32, 64); acc.w += __shfl_xor(acc.w, 32, 64);
    if (lane < 16) {
        uint2 po = *(const uint2*)(emb_b + (size_t)dst * 64 + li * 4);
        float dv = dinv[dst];
        unsigned int h0 = f2b(dv * (acc.x + blo(po.x)));
        unsigned int h1 = f2b(dv * (acc.y + bhi(po.x)));
        unsigned int h2 = f2b(dv * (acc.z + blo(po.y)));
        unsigned int h3 = f2b(dv * (acc.w + bhi(po.y)));
        uint2 p;
        p.x = h0 | (h1 << 16);
        p.y = h2 | (h3 << 16);
        *(uint2*)(zb + (size_t)dst * 64 + li * 4) = p;
    }
}

// K2: fused MFMA MLP: h2b = bf16(dinv * (relu(zb@W1 + b1) @ W2)).
//   A-frag: lane holds A[m=lane&15][k=quad*8+j]     [m120-verified layout]
//   C/D   : lane holds D[row=quad*4+r][col=lane&15] [m89/m91]
__global__ __launch_bounds__(256) void mlp_k(const unsigned short* __restrict__ zb,
                                             const uint4* __restrict__ w1p,
                                             const float* __restrict__ b1,
                                             const uint4* __restrict__ w2p,
                                             const float* __restrict__ dinv,
                                             unsigned short* __restrict__ h2b) {
    __shared__ unsigned short y1s[4][16 * 136];   // per-wave y1 strip (pad 136)
    __shared__ unsigned short h2s[4][16 * 64];    // per-wave output strip
    int tid  = threadIdx.x;
    int w    = tid >> 6, lane = tid & 63;
    int li   = lane & 15, quad = lane >> 4;
    int r0   = blockIdx.x * 64 + w * 16;
    uint4 a0u = *(const uint4*)(zb + (size_t)(r0 + li) * 64 + quad * 8);
    uint4 a1u = *(const uint4*)(zb + (size_t)(r0 + li) * 64 + 32 + quad * 8);
    bf16x8 a0 = *(bf16x8*)&a0u;
    bf16x8 a1 = *(bf16x8*)&a1u;
    unsigned short* ys = y1s[w];
#pragma unroll
    for (int ct = 0; ct < 8; ++ct) {
        uint4 b0u = w1p[(ct * 2 + 0) * 64 + lane];
        uint4 b1u = w1p[(ct * 2 + 1) * 64 + lane];
        f32x4 acc = {0.f, 0.f, 0.f, 0.f};
        acc = __builtin_amdgcn_mfma_f32_16x16x32_bf16(a0, *(bf16x8*)&b0u, acc, 0, 0, 0);
        acc = __builtin_amdgcn_mfma_f32_16x16x32_bf16(a1, *(bf16x8*)&b1u, acc, 0, 0, 0);
        float bias = b1[ct * 16 + li];
#pragma unroll
        for (int r = 0; r < 4; ++r)
            ys[(quad * 4 + r) * 136 + ct * 16 + li] = f2b(fmaxf(acc[r] + bias, 0.f));
    }
    __syncthreads();
    bf16x8 a2[4];
#pragma unroll
    for (int s = 0; s < 4; ++s) {
        uint4 au = *(const uint4*)(ys + li * 136 + s * 32 + quad * 8);
        a2[s] = *(bf16x8*)&au;
    }
    float dvr[4];
#pragma unroll
    for (int r = 0; r < 4; ++r) {
        int grow = r0 + quad * 4 + r;
        dvr[r] = (grow < N_ENT) ? dinv[grow] : 0.f;
    }
    unsigned short* hs = h2s[w];
#pragma unroll
    for (int ct = 0; ct < 4; ++ct) {
        f32x4 acc = {0.f, 0.f, 0.f, 0.f};
#pragma unroll
        for (int s = 0; s < 4; ++s) {
            uint4 bu = w2p[(ct * 4 + s) * 64 + lane];
            acc = __builtin_amdgcn_mfma_f32_16x16x32_bf16(a2[s], *(bf16x8*)&bu, acc, 0, 0, 0);
        }
#pragma unroll
        for (int r = 0; r < 4; ++r)
            hs[(quad * 4 + r) * 64 + ct * 16 + li] = f2b(acc[r] * dvr[r]);
    }
    __syncthreads();
#pragma unroll
    for (int q = 0; q < 2; ++q) {
        int t4   = lane * 2 + q;
        int rl   = t4 >> 3;
        int c0   = (t4 & 7) * 8;
        int grow = r0 + rl;
        if (grow < N_ENT) {
            *(uint4*)(h2b + (size_t)grow * 64 + c0) = *(const uint4*)(hs + rl * 64 + c0);
        } else if (grow == N_ENT) {
            uint4 zz; zz.x = 0u; zz.y = 0u; zz.z = 0u; zz.w = 0u;
            *(uint4*)(h2b + (size_t)grow * 64 + c0) = zz;
        }
    }
}

// K3: fused layer-2 aggregate + final dot for the 8192 batch items.
__global__ __launch_bounds__(256) void reduce2f_k(const int* __restrict__ u,
                                                  const int* __restrict__ iidx,
                                                  const float* __restrict__ uemb,
                                                  const int* __restrict__ row_start,
                                                  const int* __restrict__ srcs,
                                                  const unsigned short* __restrict__ h2b,
                                                  const float* __restrict__ dinv,
                                                  const float* __restrict__ b2,
                                                  float* __restrict__ out) {
    int gt   = blockIdx.x * 256 + threadIdx.x;
    int b    = gt >> 6;
    int lane = threadIdx.x & 63;
    int sub  = lane >> 4;
    int li   = lane & 15;
    int dst = iidx[b];
    int beg = row_start[dst];
    int end = row_start[dst + 1];
    float4 acc = make_float4(0.f, 0.f, 0.f, 0.f);
    for (int base = beg; base < end; base += 64) {
        int cnt = end - base; if (cnt > 64) cnt = 64;
        int s_v = (base + lane < end) ? srcs[base + lane] : N_ENT;
        for (int jj = 0; jj < cnt; jj += 16) {
            int s0 = __shfl(s_v, jj + sub,      64);
            int s1 = __shfl(s_v, jj + 4 + sub,  64);
            int s2 = __shfl(s_v, jj + 8 + sub,  64);
            int s3 = __shfl(s_v, jj + 12 + sub, 64);
            uint2 p0 = *(const uint2*)(h2b + (size_t)s0 * 64 + li * 4);
            uint2 p1 = *(const uint2*)(h2b + (size_t)s1 * 64 + li * 4);
            uint2 p2 = *(const uint2*)(h2b + (size_t)s2 * 64 + li * 4);
            uint2 p3 = *(const uint2*)(h2b + (size_t)s3 * 64 + li * 4);
            acc.x += blo(p0.x) + blo(p1.x) + blo(p2.x) + blo(p3.x);
            acc.y += bhi(p0.x) + bhi(p1.x) + bhi(p2.x) + bhi(p3.x);
            acc.z += blo(p0.y) + blo(p1.y) + blo(p2.y) + blo(p3.y);
            acc.w += bhi(p0.y) + bhi(p1.y) + bhi(p2.y) + bhi(p3.y);
        }
    }
    acc.x += __shfl_xor(acc.x, 16, 64); acc.y += __shfl_xor(acc.y, 16, 64);
    acc.z += __shfl_xor(acc.z, 16, 64); acc.w += __shfl_xor(acc.w, 16, 64);
    acc.x += __shfl_xor(acc.x, 32, 64); acc.y += __shfl_xor(acc.y, 32, 64);
    acc.z += __shfl_xor(acc.z, 32, 64); acc.w += __shfl_xor(acc.w, 32, 64);
    float s1 = 0.f, s2 = 0.f;
    if (lane < 16) {
        uint2 po = *(const uint2*)(h2b + (size_t)dst * 64 + li * 4);
        float dv = dinv[dst];
        float4 bb = *(const float4*)(b2 + li * 4);
        float4 z2v;
        z2v.x = dv * (acc.x + blo(po.x)) + bb.x;
        z2v.y = dv * (acc.y + bhi(po.x)) + bb.y;
        z2v.z = dv * (acc.z + blo(po.y)) + bb.z;
        z2v.w = dv * (acc.w + bhi(po.y)) + bb.w;
        float4 ue = *(const float4*)(uemb + (size_t)u[b] * 64 + li * 4);
        s1 = ue.x * ue.x + ue.y * ue.y + ue.z * ue.z + ue.w * ue.w;
        s2 = ue.x * z2v.x + ue.y * z2v.y + ue.z * z2v.z + ue.w * z2v.w;
    }
#pragma unroll
    for (int o = 8; o > 0; o >>= 1) {
        s1 += __shfl_xor(s1, o, 64);
        s2 += __shfl_xor(s2, o, 64);
    }
    if (lane == 0) {
        float nrm = sqrtf(s1);
        float sc  = nrm > 1.0f ? 1.0f / nrm : 1.0f;
        float uv  = s2 * sc;
        out[b] = 1.0f / (1.0f + expf(-uv));
    }
}

// ---------------------------------------------------------------------------
extern "C" void kernel_launch(void* const* d_in, const int* in_sizes, int n_in,
                              void* d_out, int out_size, void* d_ws, size_t ws_size,
                              hipStream_t stream) {
    const int*   u          = (const int*)d_in[0];
    const int*   iidx       = (const int*)d_in[1];
    const int*   edges      = (const int*)d_in[2];
    const float* user_emb   = (const float*)d_in[3];
    const float* entity_emb = (const float*)d_in[4];
    const float* W1         = (const float*)d_in[5];
    const float* b1         = (const float*)d_in[6];
    const float* W2         = (const float*)d_in[7];
    const float* b2         = (const float*)d_in[8];
    float*       out        = (float*)d_out;

    char* ws = (char*)d_ws;
    float*          dinv      = (float*)         (ws + 100000u * 4);
    int*            row_start = (int*)           (ws + 200000u * 4);
    int*            gcursor   = (int*)           (ws + 300004u * 4);
    uint4*          w1p       = (uint4*)         (ws + 300656u * 4);
    uint4*          w2p       = (uint4*)         (ws + 304752u * 4);
    int*            srcs      = (int*)           (ws + 308848u * 4);
    unsigned short* emb_b     = (unsigned short*)(ws + 1908848u * 4);  // (N+1)*64
    unsigned short* zb        = (unsigned short*)(ws + 3508864u * 4);  // 100096*64
    unsigned short* h2b       = (unsigned short*)(ws + 6711936u * 4);  // (N+1)*64
    unsigned int*   temp      = (unsigned int*)  (ws + 8311968u * 4);

    {
        void* args[12];
        args[0]  = (void*)&edges;
        args[1]  = (void*)&W1;
        args[2]  = (void*)&W2;
        args[3]  = (void*)&w1p;
        args[4]  = (void*)&w2p;
        args[5]  = (void*)&gcursor;
        args[6]  = (void*)&temp;
        args[7]  = (void*)&row_start;
        args[8]  = (void*)&srcs;
        args[9]  = (void*)&entity_emb;
        args[10] = (void*)&dinv;
        args[11] = (void*)&emb_b;
        hipLaunchCooperativeKernel((void*)pre_k, dim3(NTILE), dim3(256),
                                   args, 0, stream);
    }

    reduce1_k<<<N_ENT * 64 / 256, 256, 0, stream>>>(row_start, srcs, emb_b, dinv, zb);
    mlp_k<<<NBLK_G, 256, 0, stream>>>(zb, w1p, b1, w2p, dinv, h2b);

    reduce2f_k<<<BATCH * 64 / 256, 256, 0, stream>>>(u, iidx, user_emb, row_start,
                                                     srcs, h2b, dinv, b2, out);
}

// Round 6
// 228.870 us; speedup vs baseline: 1.6504x; 1.6504x over previous
//
#include <hip/hip_runtime.h>
#include <hip/hip_bf16.h>
#include <math.h>

// Problem constants (from reference)
constexpr int N_ENT = 100000;
constexpr int NEDGE = 1600000;
constexpr int BATCH = 8192;

// Bucketed CSR placement
constexpr int NBUCK   = 256;
constexpr int KNODE   = 391;                      // 256*391 >= N_ENT
constexpr int TILE    = 4096;
constexpr int NTILE   = (NEDGE + TILE - 1) / TILE; // 391
constexpr int BUCKCAP = 8192;                     // fixed bucket region

constexpr int NBLK_G = (N_ENT + 63) / 64;         // 1563 (64-row MLP tiles)

// [R19 journal] Cooperative grid.sync() on MI355X costs ~50us/barrier at
// 391 blocks (pre_k 197us, VALUBusy 3% -> s_sleep backoff, not spin).
// NEVER trade ~2us launch boundaries for grid.sync here. Full revert to the
// R4 8-dispatch structure; reduce1 re-merged (split's diagnostic job done).
// Budget model: 234us = 123us harness ws-poison fills (fixed) + 50us
// reduce1 (random-gather floor) + ~60us rest. Top-5 slot #5 now exposes
// the largest remaining kernel.

// MFMA fragment types (gfx950; 8 bf16 = 4 VGPRs, 4 f32 acc)
typedef __attribute__((ext_vector_type(8))) short bf16x8;
typedef __attribute__((ext_vector_type(4))) float f32x4;

// bf16 helpers (RNE pack, exact unpack)
__device__ inline unsigned short f2b(float x) {
    unsigned int u = __float_as_uint(x);
    unsigned int r = (u + 0x7fffu + ((u >> 16) & 1u)) >> 16;
    return (unsigned short)r;
}
__device__ inline float blo(unsigned int p) { return __uint_as_float(p << 16); }
__device__ inline float bhi(unsigned int p) { return __uint_as_float(p & 0xffff0000u); }

// ---------------------------------------------------------------------------
// Workspace layout (4-byte units; 41.6 MB of ws):
//  dinv      : [100000, 200000)
//  row_start : [200000, 300001)
//  gcursor   : [300004, 300260)
//  w1p       : [300656, 304752)    uint4[1024] packed W1 B-frags (bf16)
//  w2p       : [304752, 308848)    uint4[1024] packed W2 B-frags (bf16)
//  srcs      : [308848, 1908848)
//  emb_b     : [1908848, 3508864)  ushort[(N+1)*64]
//  zb        : [3508864, 6711936)  ushort[100096*64] bf16 z (padded rows)
//  h2b       : [6711936, 8311968)  ushort[(N+1)*64]
//  temp      : [8311968, 10409120) uint[256*8192]

// K0: gcursor init to fixed bucket bases
__global__ __launch_bounds__(256) void ginit_k(int* __restrict__ gcursor) {
    gcursor[threadIdx.x] = threadIdx.x * BUCKCAP;
}

// K1: bucket binning (packed staging: val = src<<9|dl, bucket ids 4x8b)
__global__ __launch_bounds__(256) void bin_k(const int* __restrict__ edges,
                                             int* __restrict__ gcursor,
                                             unsigned int* __restrict__ temp) {
    __shared__ int cnt[NBUCK];
    __shared__ int gb[NBUCK];
    __shared__ int off[NBUCK];
    int tid  = threadIdx.x;
    int base = blockIdx.x * TILE;
    unsigned int val[16];
    unsigned int bpk[4] = {0u, 0u, 0u, 0u};
    cnt[tid] = 0;
    __syncthreads();
#pragma unroll
    for (int i = 0; i < 16; ++i) {
        int e = base + i * 256 + tid;
        unsigned int b = 0u;
        if (e < NEDGE) {
            int s  = edges[e];
            int d  = edges[NEDGE + e];
            int bb = d / KNODE;            // magic-mul
            int dl = d - bb * KNODE;
            val[i] = ((unsigned int)s << 9) | (unsigned int)dl;
            b = (unsigned int)bb;
            atomicAdd(&cnt[bb], 1);
        } else {
            val[i] = 0xffffffffu;          // invalid marker (valid < 2^26)
        }
        bpk[i >> 2] |= b << ((i & 3) * 8);
    }
    __syncthreads();
    if (cnt[tid] > 0) gb[tid] = atomicAdd(&gcursor[tid], cnt[tid]);
    off[tid] = 0;
    __syncthreads();
#pragma unroll
    for (int i = 0; i < 16; ++i) {
        if (val[i] != 0xffffffffu) {
            int b = (int)((bpk[i >> 2] >> ((i & 3) * 8)) & 255u);
            int p = atomicAdd(&off[b], 1);
            temp[gb[b] + p] = val[i];
        }
    }
}

// K2: fused count + scan + placement (+ packw in blocks 256..263).
// Blocks 0..255: stage bucket's temp in LDS (read once), histogram,
// in-block scan of gcursor deltas -> bucket_base, wave-scan of 391 node
// degrees -> row_start + cur, then place srcs from LDS.
__global__ __launch_bounds__(256) void unbinC_k(const unsigned int* __restrict__ temp,
                                                const int* __restrict__ gcursor,
                                                const float* __restrict__ W1g,
                                                const float* __restrict__ W2g,
                                                uint4* __restrict__ w1p,
                                                uint4* __restrict__ w2p,
                                                int* __restrict__ row_start,
                                                int* __restrict__ srcs) {
    __shared__ unsigned int st[BUCKCAP];   // 32 KB bucket stage
    __shared__ int bs[NBUCK];
    __shared__ int cnt[KNODE];
    __shared__ int cur[KNODE];
    int b   = blockIdx.x;
    int tid = threadIdx.x;
    if (b >= NBUCK) {
        // weight pack: 8 blocks -> 2048 threads
        int t    = (b - NBUCK) * 256 + tid;
        int e    = t & 1023;
        int lane = e & 63, cs = e >> 6;
        int li   = lane & 15, quad = lane >> 4;
        unsigned short v[8];
        if (t < 1024) {
            int ct = cs >> 1, s = cs & 1;
            int kb = s * 32 + quad * 8;
            int n  = ct * 16 + li;
#pragma unroll
            for (int j = 0; j < 8; ++j) v[j] = f2b(W1g[(kb + j) * 128 + n]);
            uint4 p;
            p.x = (unsigned)v[0] | ((unsigned)v[1] << 16);
            p.y = (unsigned)v[2] | ((unsigned)v[3] << 16);
            p.z = (unsigned)v[4] | ((unsigned)v[5] << 16);
            p.w = (unsigned)v[6] | ((unsigned)v[7] << 16);
            w1p[e] = p;
        } else {
            int ct = cs >> 2, s = cs & 3;
            int kb = s * 32 + quad * 8;
            int n  = ct * 16 + li;
#pragma unroll
            for (int j = 0; j < 8; ++j) v[j] = f2b(W2g[(kb + j) * 64 + n]);
            uint4 p;
            p.x = (unsigned)v[0] | ((unsigned)v[1] << 16);
            p.y = (unsigned)v[2] | ((unsigned)v[3] << 16);
            p.z = (unsigned)v[4] | ((unsigned)v[5] << 16);
            p.w = (unsigned)v[6] | ((unsigned)v[7] << 16);
            w2p[e] = p;
        }
        return;
    }
    // bucket_base: in-block exclusive scan of per-bucket counts
    int myc = gcursor[tid] - tid * BUCKCAP;
    bs[tid] = myc;
    __syncthreads();
    for (int off = 1; off < NBUCK; off <<= 1) {
        int x = (tid >= off) ? bs[tid - off] : 0;
        __syncthreads();
        bs[tid] += x;
        __syncthreads();
    }
    int node0 = b * KNODE;
    int nn    = N_ENT - node0; if (nn > KNODE) nn = KNODE;
    int tbeg  = b * BUCKCAP;
    int m     = gcursor[b] - tbeg;
    int bucket_base = bs[b] - m;
    for (int i = tid; i < KNODE; i += 256) cnt[i] = 0;
    __syncthreads();
    // stage + histogram (single global read of temp)
    for (int i = tid; i < m; i += 256) {
        unsigned int x = temp[tbeg + i];
        st[i] = x;
        atomicAdd(&cnt[x & 511u], 1);
    }
    if (b == 0 && tid == 255) row_start[N_ENT] = NEDGE;
    __syncthreads();
    // wave 0: 391-element prefix scan (7/lane) -> cur + row_start
    if (tid < 64) {
        int lane = tid;
        int loc[7];
        int s = 0;
#pragma unroll
        for (int j = 0; j < 7; ++j) {
            int idx = lane * 7 + j;
            int d = (idx < nn) ? cnt[idx] : 0;
            loc[j] = s;
            s += d;
        }
        int v = s;
#pragma unroll
        for (int o = 1; o < 64; o <<= 1) {
            int x = __shfl_up(v, o, 64);
            if (lane >= o) v += x;
        }
        int pfx = v - s;
#pragma unroll
        for (int j = 0; j < 7; ++j) {
            int idx = lane * 7 + j;
            if (idx < nn) {
                int rs = bucket_base + pfx + loc[j];
                cur[idx] = rs;
                row_start[node0 + idx] = rs;
            }
        }
    }
    __syncthreads();
    // placement from LDS
    for (int i = tid; i < m; i += 256) {
        unsigned int x = st[i];
        int dl  = (int)(x & 511u);
        int pos = atomicAdd(&cur[dl], 1);
        srcs[pos] = (int)(x >> 9);
    }
}

// K3: prep — dinv (from row_start diff) + premultiplied bf16 entity rows
// (+ zero row at N_ENT)
__global__ __launch_bounds__(256) void prep_k(const float* __restrict__ emb,
                                              const int* __restrict__ row_start,
                                              float* __restrict__ dinv,
                                              unsigned short* __restrict__ emb_b) {
    int gt   = blockIdx.x * 256 + threadIdx.x;
    int n    = gt >> 6;
    int lane = threadIdx.x & 63;
    if (n > N_ENT) return;
    if (n == N_ENT) { emb_b[(size_t)n * 64 + lane] = 0; return; }
    float v = emb[(size_t)n * 64 + lane];
    float s = v * v;
#pragma unroll
    for (int o = 32; o > 0; o >>= 1) s += __shfl_xor(s, o, 64);
    float nrm = sqrtf(s);
    float sc  = nrm > 1.0f ? 1.0f / nrm : 1.0f;
    int   deg = row_start[n + 1] - row_start[n];
    float dv  = 1.0f / sqrtf((float)(deg + 1));
    if (lane == 0) dinv[n] = dv;
    emb_b[(size_t)n * 64 + lane] = f2b(sc * dv * v);
}

// K4: layer-1 aggregate (uint2, 16 lanes/row — best measured, ~49.8us;
// pinned at the random-128B-row gather floor across 3 structural variants).
__global__ __launch_bounds__(256) void reduce1_k(const int* __restrict__ row_start,
                                                 const int* __restrict__ srcs,
                                                 const unsigned short* __restrict__ emb_b,
                                                 const float* __restrict__ dinv,
                                                 unsigned short* __restrict__ zb) {
    int gt   = blockIdx.x * 256 + threadIdx.x;
    int dst  = gt >> 6;
    int lane = threadIdx.x & 63;
    int sub  = lane >> 4;
    int li   = lane & 15;
    int beg = row_start[dst];
    int end = row_start[dst + 1];
    float4 acc = make_float4(0.f, 0.f, 0.f, 0.f);
    for (int base = beg; base < end; base += 64) {
        int cnt = end - base; if (cnt > 64) cnt = 64;
        int s_v = (base + lane < end) ? srcs[base + lane] : N_ENT;
        for (int jj = 0; jj < cnt; jj += 16) {
            int s0 = __shfl(s_v, jj + sub,      64);
            int s1 = __shfl(s_v, jj + 4 + sub,  64);
            int s2 = __shfl(s_v, jj + 8 + sub,  64);
            int s3 = __shfl(s_v, jj + 12 + sub, 64);
            uint2 p0 = *(const uint2*)(emb_b + (size_t)s0 * 64 + li * 4);
            uint2 p1 = *(const uint2*)(emb_b + (size_t)s1 * 64 + li * 4);
            uint2 p2 = *(const uint2*)(emb_b + (size_t)s2 * 64 + li * 4);
            uint2 p3 = *(const uint2*)(emb_b + (size_t)s3 * 64 + li * 4);
            acc.x += blo(p0.x) + blo(p1.x) + blo(p2.x) + blo(p3.x);
            acc.y += bhi(p0.x) + bhi(p1.x) + bhi(p2.x) + bhi(p3.x);
            acc.z += blo(p0.y) + blo(p1.y) + blo(p2.y) + blo(p3.y);
            acc.w += bhi(p0.y) + bhi(p1.y) + bhi(p2.y) + bhi(p3.y);
        }
    }
    acc.x += __shfl_xor(acc.x, 16, 64); acc.y += __shfl_xor(acc.y, 16, 64);
    acc.z += __shfl_xor(acc.z, 16, 64); acc.w += __shfl_xor(acc.w, 16, 64);
    acc.x += __shfl_xor(acc.x, 32, 64); acc.y += __shfl_xor(acc.y, 32, 64);
    acc.z += __shfl_xor(acc.z, 32, 64); acc.w += __shfl_xor(acc.w, 32, 64);
    if (lane < 16) {
        uint2 po = *(const uint2*)(emb_b + (size_t)dst * 64 + li * 4);
        float dv = dinv[dst];
        unsigned int h0 = f2b(dv * (acc.x + blo(po.x)));
        unsigned int h1 = f2b(dv * (acc.y + bhi(po.x)));
        unsigned int h2 = f2b(dv * (acc.z + blo(po.y)));
        unsigned int h3 = f2b(dv * (acc.w + bhi(po.y)));
        uint2 p;
        p.x = h0 | (h1 << 16);
        p.y = h2 | (h3 << 16);
        *(uint2*)(zb + (size_t)dst * 64 + li * 4) = p;
    }
}

// K5: fused MFMA MLP: h2b = bf16(dinv * (relu(zb@W1 + b1) @ W2)).
//   A-frag: lane holds A[m=lane&15][k=quad*8+j]     [m120-verified layout]
//   C/D   : lane holds D[row=quad*4+r][col=lane&15] [m89/m91]
__global__ __launch_bounds__(256) void mlp_k(const unsigned short* __restrict__ zb,
                                             const uint4* __restrict__ w1p,
                                             const float* __restrict__ b1,
                                             const uint4* __restrict__ w2p,
                                             const float* __restrict__ dinv,
                                             unsigned short* __restrict__ h2b) {
    __shared__ unsigned short y1s[4][16 * 136];   // per-wave y1 strip (pad 136)
    __shared__ unsigned short h2s[4][16 * 64];    // per-wave output strip
    int tid  = threadIdx.x;
    int w    = tid >> 6, lane = tid & 63;
    int li   = lane & 15, quad = lane >> 4;
    int r0   = blockIdx.x * 64 + w * 16;
    uint4 a0u = *(const uint4*)(zb + (size_t)(r0 + li) * 64 + quad * 8);
    uint4 a1u = *(const uint4*)(zb + (size_t)(r0 + li) * 64 + 32 + quad * 8);
    bf16x8 a0 = *(bf16x8*)&a0u;
    bf16x8 a1 = *(bf16x8*)&a1u;
    unsigned short* ys = y1s[w];
#pragma unroll
    for (int ct = 0; ct < 8; ++ct) {
        uint4 b0u = w1p[(ct * 2 + 0) * 64 + lane];
        uint4 b1u = w1p[(ct * 2 + 1) * 64 + lane];
        f32x4 acc = {0.f, 0.f, 0.f, 0.f};
        acc = __builtin_amdgcn_mfma_f32_16x16x32_bf16(a0, *(bf16x8*)&b0u, acc, 0, 0, 0);
        acc = __builtin_amdgcn_mfma_f32_16x16x32_bf16(a1, *(bf16x8*)&b1u, acc, 0, 0, 0);
        float bias = b1[ct * 16 + li];
#pragma unroll
        for (int r = 0; r < 4; ++r)
            ys[(quad * 4 + r) * 136 + ct * 16 + li] = f2b(fmaxf(acc[r] + bias, 0.f));
    }
    __syncthreads();
    bf16x8 a2[4];
#pragma unroll
    for (int s = 0; s < 4; ++s) {
        uint4 au = *(const uint4*)(ys + li * 136 + s * 32 + quad * 8);
        a2[s] = *(bf16x8*)&au;
    }
    float dvr[4];
#pragma unroll
    for (int r = 0; r < 4; ++r) {
        int grow = r0 + quad * 4 + r;
        dvr[r] = (grow < N_ENT) ? dinv[grow] : 0.f;
    }
    unsigned short* hs = h2s[w];
#pragma unroll
    for (int ct = 0; ct < 4; ++ct) {
        f32x4 acc = {0.f, 0.f, 0.f, 0.f};
#pragma unroll
        for (int s = 0; s < 4; ++s) {
            uint4 bu = w2p[(ct * 4 + s) * 64 + lane];
            acc = __builtin_amdgcn_mfma_f32_16x16x32_bf16(a2[s], *(bf16x8*)&bu, acc, 0, 0, 0);
        }
#pragma unroll
        for (int r = 0; r < 4; ++r)
            hs[(quad * 4 + r) * 64 + ct * 16 + li] = f2b(acc[r] * dvr[r]);
    }
    __syncthreads();
#pragma unroll
    for (int q = 0; q < 2; ++q) {
        int t4   = lane * 2 + q;
        int rl   = t4 >> 3;
        int c0   = (t4 & 7) * 8;
        int grow = r0 + rl;
        if (grow < N_ENT) {
            *(uint4*)(h2b + (size_t)grow * 64 + c0) = *(const uint4*)(hs + rl * 64 + c0);
        } else if (grow == N_ENT) {
            uint4 zz; zz.x = 0u; zz.y = 0u; zz.z = 0u; zz.w = 0u;
            *(uint4*)(h2b + (size_t)grow * 64 + c0) = zz;
        }
    }
}

// K6: fused layer-2 aggregate + final dot for the 8192 batch items.
__global__ __launch_bounds__(256) void reduce2f_k(const int* __restrict__ u,
                                                  const int* __restrict__ iidx,
                                                  const float* __restrict__ uemb,
                                                  const int* __restrict__ row_start,
                                                  const int* __restrict__ srcs,
                                                  const unsigned short* __restrict__ h2b,
                                                  const float* __restrict__ dinv,
                                                  const float* __restrict__ b2,
                                                  float* __restrict__ out) {
    int gt   = blockIdx.x * 256 + threadIdx.x;
    int b    = gt >> 6;
    int lane = threadIdx.x & 63;
    int sub  = lane >> 4;
    int li   = lane & 15;
    int dst = iidx[b];
    int beg = row_start[dst];
    int end = row_start[dst + 1];
    float4 acc = make_float4(0.f, 0.f, 0.f, 0.f);
    for (int base = beg; base < end; base += 64) {
        int cnt = end - base; if (cnt > 64) cnt = 64;
        int s_v = (base + lane < end) ? srcs[base + lane] : N_ENT;
        for (int jj = 0; jj < cnt; jj += 16) {
            int s0 = __shfl(s_v, jj + sub,      64);
            int s1 = __shfl(s_v, jj + 4 + sub,  64);
            int s2 = __shfl(s_v, jj + 8 + sub,  64);
            int s3 = __shfl(s_v, jj + 12 + sub, 64);
            uint2 p0 = *(const uint2*)(h2b + (size_t)s0 * 64 + li * 4);
            uint2 p1 = *(const uint2*)(h2b + (size_t)s1 * 64 + li * 4);
            uint2 p2 = *(const uint2*)(h2b + (size_t)s2 * 64 + li * 4);
            uint2 p3 = *(const uint2*)(h2b + (size_t)s3 * 64 + li * 4);
            acc.x += blo(p0.x) + blo(p1.x) + blo(p2.x) + blo(p3.x);
            acc.y += bhi(p0.x) + bhi(p1.x) + bhi(p2.x) + bhi(p3.x);
            acc.z += blo(p0.y) + blo(p1.y) + blo(p2.y) + blo(p3.y);
            acc.w += bhi(p0.y) + bhi(p1.y) + bhi(p2.y) + bhi(p3.y);
        }
    }
    acc.x += __shfl_xor(acc.x, 16, 64); acc.y += __shfl_xor(acc.y, 16, 64);
    acc.z += __shfl_xor(acc.z, 16, 64); acc.w += __shfl_xor(acc.w, 16, 64);
    acc.x += __shfl_xor(acc.x, 32, 64); acc.y += __shfl_xor(acc.y, 32, 64);
    acc.z += __shfl_xor(acc.z, 32, 64); acc.w += __shfl_xor(acc.w, 32, 64);
    float s1 = 0.f, s2 = 0.f;
    if (lane < 16) {
        uint2 po = *(const uint2*)(h2b + (size_t)dst * 64 + li * 4);
        float dv = dinv[dst];
        float4 bb = *(const float4*)(b2 + li * 4);
        float4 z2v;
        z2v.x = dv * (acc.x + blo(po.x)) + bb.x;
        z2v.y = dv * (acc.y + bhi(po.x)) + bb.y;
        z2v.z = dv * (acc.z + blo(po.y)) + bb.z;
        z2v.w = dv * (acc.w + bhi(po.y)) + bb.w;
        float4 ue = *(const float4*)(uemb + (size_t)u[b] * 64 + li * 4);
        s1 = ue.x * ue.x + ue.y * ue.y + ue.z * ue.z + ue.w * ue.w;
        s2 = ue.x * z2v.x + ue.y * z2v.y + ue.z * z2v.z + ue.w * z2v.w;
    }
#pragma unroll
    for (int o = 8; o > 0; o >>= 1) {
        s1 += __shfl_xor(s1, o, 64);
        s2 += __shfl_xor(s2, o, 64);
    }
    if (lane == 0) {
        float nrm = sqrtf(s1);
        float sc  = nrm > 1.0f ? 1.0f / nrm : 1.0f;
        float uv  = s2 * sc;
        out[b] = 1.0f / (1.0f + expf(-uv));
    }
}

// ---------------------------------------------------------------------------
extern "C" void kernel_launch(void* const* d_in, const int* in_sizes, int n_in,
                              void* d_out, int out_size, void* d_ws, size_t ws_size,
                              hipStream_t stream) {
    const int*   u          = (const int*)d_in[0];
    const int*   iidx       = (const int*)d_in[1];
    const int*   edges      = (const int*)d_in[2];
    const float* user_emb   = (const float*)d_in[3];
    const float* entity_emb = (const float*)d_in[4];
    const float* W1         = (const float*)d_in[5];
    const float* b1         = (const float*)d_in[6];
    const float* W2         = (const float*)d_in[7];
    const float* b2         = (const float*)d_in[8];
    float*       out        = (float*)d_out;

    char* ws = (char*)d_ws;
    float*          dinv      = (float*)         (ws + 100000u * 4);
    int*            row_start = (int*)           (ws + 200000u * 4);
    int*            gcursor   = (int*)           (ws + 300004u * 4);
    uint4*          w1p       = (uint4*)         (ws + 300656u * 4);
    uint4*          w2p       = (uint4*)         (ws + 304752u * 4);
    int*            srcs      = (int*)           (ws + 308848u * 4);
    unsigned short* emb_b     = (unsigned short*)(ws + 1908848u * 4);  // (N+1)*64
    unsigned short* zb        = (unsigned short*)(ws + 3508864u * 4);  // 100096*64
    unsigned short* h2b       = (unsigned short*)(ws + 6711936u * 4);  // (N+1)*64
    unsigned int*   temp      = (unsigned int*)  (ws + 8311968u * 4);

    ginit_k<<<1, 256, 0, stream>>>(gcursor);
    bin_k<<<NTILE, 256, 0, stream>>>(edges, gcursor, temp);
    unbinC_k<<<NBUCK + 8, 256, 0, stream>>>(temp, gcursor, W1, W2, w1p, w2p,
                                            row_start, srcs);
    prep_k<<<N_ENT * 64 / 256 + 1, 256, 0, stream>>>(entity_emb, row_start,
                                                     dinv, emb_b);

    reduce1_k<<<N_ENT * 64 / 256, 256, 0, stream>>>(row_start, srcs, emb_b, dinv, zb);
    mlp_k<<<NBLK_G, 256, 0, stream>>>(zb, w1p, b1, w2p, dinv, h2b);

    reduce2f_k<<<BATCH * 64 / 256, 256, 0, stream>>>(u, iidx, user_emb, row_start,
                                                     srcs, h2b, dinv, b2, out);
}